// Round 13
// baseline (438.389 us; speedup 1.0000x reference)
//
#include <hip/hip_runtime.h>

typedef __bf16 bf16;
typedef __bf16 bf16x8 __attribute__((ext_vector_type(8)));
typedef __bf16 bf16x4 __attribute__((ext_vector_type(4)));
typedef float  f32x4  __attribute__((ext_vector_type(4)));
typedef float  f32x16 __attribute__((ext_vector_type(16)));
typedef unsigned int u32;
typedef int i32x2 __attribute__((ext_vector_type(2)));
typedef int i32x4 __attribute__((ext_vector_type(4)));

#define NB 4
#define NS 2048
#define ND 1024
#define NH 16
#define NDK 64
#define NFF 4096
#define NM (NB*NS)   // 8192 rows

// scale folded into Q projection: (1/sqrt(64)) * log2(e)
#define QSCALE 0.18033688f

__device__ __forceinline__ void load_lds16(const void* g, void* l) {
  __builtin_amdgcn_global_load_lds(
      (const __attribute__((address_space(1))) void*)g,
      (__attribute__((address_space(3))) void*)l, 16, 0, 0);
}

__device__ __forceinline__ u32 pack2(float a, float b) {
  union { bf16 h[2]; u32 u; } z;
  z.h[0] = (bf16)a; z.h[1] = (bf16)b;
  return z.u;
}

__device__ __forceinline__ i32x2 pswap(u32 a, u32 b) {
#if __has_builtin(__builtin_amdgcn_permlane32_swap)
  return __builtin_amdgcn_permlane32_swap((int)a, (int)b, false, false);
#else
  u32 x = a, y = b;
  asm volatile("v_permlane32_swap_b32 %0, %1" : "+v"(x), "+v"(y));
  i32x2 r; r[0] = (int)x; r[1] = (int)y; return r;
#endif
}

// ---------------------------------------------------------------- prep (merged)
__device__ __forceinline__ void tc_body(const float* __restrict__ ip,
                                        bf16* __restrict__ op, int R, int C,
                                        float (*t)[33], int tid) {
  int x = tid & 31, y = tid >> 5;
#pragma unroll
  for (int yy = 0; yy < 32; yy += 8)
    t[y + yy][x] = ip[(size_t)(y + yy) * C + x];
  __syncthreads();
#pragma unroll
  for (int yy = 0; yy < 32; yy += 8)
    op[(size_t)(y + yy) * R + x] = (bf16)t[x][y + yy];
}

__global__ __launch_bounds__(256)
void prep_all(const float* __restrict__ src, bf16* __restrict__ srcb,
              const float* __restrict__ wq, const float* __restrict__ wk,
              const float* __restrict__ wv, bf16* __restrict__ wqkvT,
              const float* __restrict__ wo, bf16* __restrict__ woT,
              const float* __restrict__ w1, bf16* __restrict__ w1T,
              const float* __restrict__ w2, bf16* __restrict__ w2T) {
  __shared__ float t[32][33];
  const int id = blockIdx.x, tid = threadIdx.x;
  if (id < 8192) {
    int i = (id * 256 + tid) * 4;
    float4 v = *(const float4*)&src[i];
    bf16x4 o;
    o[0] = (bf16)v.x; o[1] = (bf16)v.y; o[2] = (bf16)v.z; o[3] = (bf16)v.w;
    *(bf16x4*)&srcb[i] = o;
    return;
  }
  int id2 = id - 8192;
  if (id2 < 3072) {
    int wsel = id2 >> 10, r = id2 & 1023;
    int bz = r >> 6, by = (r >> 5) & 1, bx = r & 31;
    const float* w = (wsel == 0) ? wq : (wsel == 1) ? wk : wv;
    const float* ip = w + (size_t)bz * 65536 + (size_t)(bx * 32) * 64 + by * 32;
    bf16* op = wqkvT + (size_t)wsel * 1048576 + (size_t)bz * 65536 +
               (size_t)(by * 32) * 1024 + bx * 32;
    tc_body(ip, op, 1024, 64, t, tid);
    return;
  }
  id2 -= 3072;
  if (id2 < 1024) {
    int bx = id2 & 31, by = id2 >> 5;
    const float* ip = wo + (size_t)(bx * 32) * 1024 + by * 32;
    bf16* op = woT + (size_t)(by * 32) * 1024 + bx * 32;
    tc_body(ip, op, 1024, 1024, t, tid);
    return;
  }
  id2 -= 1024;
  if (id2 < 4096) {
    int bx = id2 & 31, by = id2 >> 5;
    const float* ip = w1 + (size_t)(bx * 32) * 4096 + by * 32;
    bf16* op = w1T + (size_t)(by * 32) * 1024 + bx * 32;
    tc_body(ip, op, 1024, 4096, t, tid);
    return;
  }
  id2 -= 4096;
  {
    int bx = id2 & 127, by = id2 >> 7;
    const float* ip = w2 + (size_t)(bx * 32) * 1024 + by * 32;
    bf16* op = w2T + (size_t)(by * 32) * 4096 + bx * 32;
    tc_body(ip, op, 4096, 1024, t, tid);
  }
}

// ---------------------------------------------------------------- GEMM 8-phase
#define BAR()  __builtin_amdgcn_s_barrier()
#define LGKM0() do { asm volatile("s_waitcnt lgkmcnt(0)" ::: "memory"); \
                     __builtin_amdgcn_sched_barrier(0); } while (0)

// EPI 0: QKV scatter (q/k rows bf16 + QSCALE on q; V written TRANSPOSED to out1)
// EPI 1: bf16+relu; EPI 2: f32+bias; EPI 3: bf16+bias
template<int BN, int EPI>
__global__ __launch_bounds__(512, 2)
void gemm8p(const bf16* __restrict__ A, const bf16* __restrict__ Bt,
            const float* __restrict__ bias0, const float* __restrict__ bias1,
            const float* __restrict__ bias2, void* __restrict__ out0,
            void* __restrict__ out1, int M, int N, int K) {
  constexpr int NFR = BN / 64;          // n-frags per wave (4 or 2)
  __shared__ __align__(16) bf16 lA[2][256 * 64];
  __shared__ __align__(16) bf16 lB[2][BN * 64];

  const int tid = threadIdx.x, lane = tid & 63, w = tid >> 6;
  const int wr = w >> 2, wn = w & 3;
  const int blane = lane & 15, glane = lane >> 4;

  const int nwg = gridDim.x;
  const int cpx = nwg >> 3;
  const int bid = blockIdx.x;
  const int swzb = (bid & 7) * cpx + (bid >> 3);
  const int gridM = M >> 8;
  const int bm = (swzb % gridM) * 256;
  const int bn = (swzb / gridM) * BN;

  f32x4 acc[8][NFR] = {};
  bf16x8 aF[8], bF[2 * NFR];

  auto stageA = [&](int kt, int h, int b) {
#pragma unroll
    for (int j = 0; j < 2; j++) {
      int ch = w * 128 + j * 64 + lane;
      int r = h * 128 + (ch >> 3), s = ch & 7;
      load_lds16(A + (size_t)(bm + r) * K + kt * 64 + ((s ^ (r & 7)) * 8),
                 &lA[b][(h * 1024 + ch) * 8]);
    }
  };
  auto stageB = [&](int kt, int h, int b) {
    if constexpr (BN == 256) {
#pragma unroll
      for (int j = 0; j < 2; j++) {
        int ch = w * 128 + j * 64 + lane;
        int r = h * 128 + (ch >> 3), s = ch & 7;
        load_lds16(Bt + (size_t)(bn + r) * K + kt * 64 + ((s ^ (r & 7)) * 8),
                   &lB[b][(h * 1024 + ch) * 8]);
      }
    } else {
      int ch = w * 64 + lane;
      int r = h * 64 + (ch >> 3), s = ch & 7;
      load_lds16(Bt + (size_t)(bn + r) * K + kt * 64 + ((s ^ (r & 7)) * 8),
                 &lB[b][(h * 512 + ch) * 8]);
    }
  };
  auto vmwait = [&]() {
    if constexpr (BN == 256) asm volatile("s_waitcnt vmcnt(6)" ::: "memory");
    else                     asm volatile("s_waitcnt vmcnt(4)" ::: "memory");
  };
  auto ldA = [&](int mh, int b) {
#pragma unroll
    for (int mf = 0; mf < 4; mf++)
#pragma unroll
      for (int ks = 0; ks < 2; ks++) {
        int r = wr * 128 + mh * 64 + mf * 16 + blane;
        int s = (ks * 4 + glane) ^ (r & 7);
        aF[mf * 2 + ks] = *(const bf16x8*)&lA[b][r * 64 + s * 8];
      }
  };
  auto ldBh = [&](int nh, int b) {
#pragma unroll
    for (int nq = 0; nq < NFR / 2; nq++)
#pragma unroll
      for (int ks = 0; ks < 2; ks++) {
        int nf = nh * (NFR / 2) + nq;
        int r = wn * (NFR * 16) + nf * 16 + blane;
        int s = (ks * 4 + glane) ^ (r & 7);
        bF[nf * 2 + ks] = *(const bf16x8*)&lB[b][r * 64 + s * 8];
      }
  };

#define MMAQ(mh, nh)  do {                                                  \
    __builtin_amdgcn_s_setprio(1);                                          \
    _Pragma("unroll")                                                       \
    for (int mf = 0; mf < 4; mf++)                                          \
      _Pragma("unroll")                                                     \
      for (int nq = 0; nq < NFR / 2; nq++)                                  \
        _Pragma("unroll")                                                   \
        for (int ks = 0; ks < 2; ks++)                                      \
          acc[(mh) * 4 + mf][(nh) * (NFR / 2) + nq] =                       \
            __builtin_amdgcn_mfma_f32_16x16x32_bf16(                        \
              aF[mf * 2 + ks], bF[((nh) * (NFR / 2) + nq) * 2 + ks],        \
              acc[(mh) * 4 + mf][(nh) * (NFR / 2) + nq], 0, 0, 0);          \
    __builtin_amdgcn_s_setprio(0);                                          \
  } while (0)

  // ---- prologue: tile0 full + tile1 {B0,B1,A0}
  stageB(0, 0, 0); stageB(0, 1, 0); stageA(0, 0, 0); stageA(0, 1, 0);
  stageB(1, 0, 1); stageB(1, 1, 1); stageA(1, 0, 1);
  vmwait();
  BAR();

  const int NT = K >> 6;
  for (int u = 0; u < NT; u += 2) {
    const int t2 = (u + 2 < NT) ? u + 2 : u;
    const int t3 = (u + 3 < NT) ? u + 3 : u + 1;
    // P1
    ldA(0, 0); ldBh(0, 0);
    stageA(u + 1, 1, 1);
    BAR(); LGKM0(); MMAQ(0, 0); BAR();
    // P2
    ldBh(1, 0);
    stageB(t2, 0, 0);
    BAR(); LGKM0(); MMAQ(0, 1); BAR();
    // P3
    ldA(1, 0);
    stageB(t2, 1, 0);
    BAR(); LGKM0(); MMAQ(1, 1); BAR();
    // P4
    stageA(t2, 0, 0);
    BAR(); MMAQ(1, 0); vmwait(); BAR();
    // P5
    ldA(0, 1); ldBh(0, 1);
    stageA(t2, 1, 0);
    BAR(); LGKM0(); MMAQ(0, 0); BAR();
    // P6
    ldBh(1, 1);
    stageB(t3, 0, 1);
    BAR(); LGKM0(); MMAQ(0, 1); BAR();
    // P7
    ldA(1, 1);
    stageB(t3, 1, 1);
    BAR(); LGKM0(); MMAQ(1, 1); BAR();
    // P8
    stageA(t3, 0, 1);
    BAR(); MMAQ(1, 0); vmwait(); BAR();
  }

  // ---- epilogue
#pragma unroll
  for (int am = 0; am < 8; am++) {
#pragma unroll
    for (int nf = 0; nf < NFR; nf++) {
      int col = bn + wn * (NFR * 16) + nf * 16 + blane;
      int rowb = bm + wr * 128 + (am >> 2) * 64 + (am & 3) * 16 + glane * 4;
      if (EPI == 0) {
        int sel = col >> 10;
        int hh = (col & 1023) >> 6;
        int dv = col & 63;
        int b_ = rowb >> 11, s_ = rowb & 2047;
        if (sel == 2) {
          // V: write transposed directly (vT[bh][dv][s]); s contiguous -> packed
          float bias = bias2[col & 1023];
          bf16* vt = (bf16*)out1;
          bf16* p = vt + (((size_t)(b_ * NH + hh) * NDK + dv) * NS) + s_;
          *(u32*)p       = pack2(acc[am][nf][0] + bias, acc[am][nf][1] + bias);
          *(u32*)(p + 2) = pack2(acc[am][nf][2] + bias, acc[am][nf][3] + bias);
        } else {
          const float* bp = (sel == 0) ? bias0 : bias1;
          float bias = bp[col & 1023];
          float sc = (sel == 0) ? QSCALE : 1.0f;   // fold softmax scale into Q
          bf16* outb = (bf16*)out0 + (size_t)sel * NB * NH * NS * NDK;
#pragma unroll
          for (int i = 0; i < 4; i++) {
            outb[(((size_t)(b_ * NH + hh) * NS + (s_ + i)) * NDK) + dv] =
                (bf16)((acc[am][nf][i] + bias) * sc);
          }
        }
      } else if (EPI == 1) {
        float bias = bias0[col];
#pragma unroll
        for (int i = 0; i < 4; i++) {
          float v = acc[am][nf][i] + bias;
          v = v > 0.f ? v : 0.f;
          ((bf16*)out0)[(size_t)(rowb + i) * N + col] = (bf16)v;
        }
      } else if (EPI == 2) {
        float bias = bias0[col];
#pragma unroll
        for (int i = 0; i < 4; i++)
          ((float*)out0)[(size_t)(rowb + i) * N + col] = acc[am][nf][i] + bias;
      } else {
        float bias = bias0[col];
#pragma unroll
        for (int i = 0; i < 4; i++)
          ((bf16*)out0)[(size_t)(rowb + i) * N + col] = (bf16)(acc[am][nf][i] + bias);
      }
    }
  }
#undef MMAQ
}

// ---------------------------------------------------------------- flash attn v7
// T14 async-STAGE split (global->reg->LDS), raw barriers (no vmcnt drain),
// 8 waves x 32 q-rows (QBLK=256), bh-clustered XCD decode, static-max softmax.
__global__ __launch_bounds__(512)
void flash_attn7(const bf16* __restrict__ q, const bf16* __restrict__ k,
                 const bf16* __restrict__ vT, bf16* __restrict__ o) {
  __shared__ __align__(16) bf16 lK[2][64 * 64];
  __shared__ __align__(16) bf16 lV[2][64 * 64];
  const int tid = threadIdx.x, lane = tid & 63, w = tid >> 6;
  const int ql = lane & 31, hi = lane >> 5;

  // XCD-clustered decode: each XCD owns 8 heads; 8 qt-blocks per head.
  const int id = blockIdx.x;
  const int xcd = id & 7, sseq = id >> 3;      // sseq 0..63
  const int bh = xcd * 8 + (sseq >> 3);
  const int qt = sseq & 7;

  const size_t hb = (size_t)bh * NS * NDK;
  const int qrow = qt * 256 + w * 32 + ql;

  // Q fragments: B-operand, col=q (lane-local), k = d = 16*ks + 8*hi + j
  bf16x8 qf[4];
#pragma unroll
  for (int ks = 0; ks < 4; ks++)
    qf[ks] = *(const bf16x8*)&q[hb + (size_t)qrow * NDK + ks * 16 + hi * 8];

  // reg-staging source (pre-swizzled 16B chunk within 128B row)
  const int sr = tid >> 3, sc = ((tid & 7) ^ (sr & 7)) * 8;
  const bf16* ksrc = k  + hb + (size_t)sr * NDK + sc;
  const bf16* vsrc = vT + hb + (size_t)sr * NS  + sc;

  f32x16 o0 = {}, o1 = {};
  float ls0 = 0.f, ls1 = 0.f, ls2 = 0.f, ls3 = 0.f;
  const int swz = (ql & 7) << 4;

  // ---- prologue: stage tile 0 via regs
  {
    i32x4 rk = *(const i32x4*)ksrc;
    i32x4 rv = *(const i32x4*)vsrc;
    *(i32x4*)&lK[0][tid * 8] = rk;
    *(i32x4*)&lV[0][tid * 8] = rv;
  }
  asm volatile("s_waitcnt lgkmcnt(0)" ::: "memory");
  __builtin_amdgcn_sched_barrier(0);
  __builtin_amdgcn_s_barrier();

  const char* lKc = (const char*)&lK[0][0];
  const char* lVc = (const char*)&lV[0][0];

  for (int t = 0; t < NS / 64; t++) {
    const int cur = t & 1;
    const char* Kb = lKc + cur * 8192;
    const char* Vb = lVc + cur * 8192;

    // ---- issue next-tile loads early (latency hides under softmax+PV)
    i32x4 nk, nv;
    const bool pf = (t < NS / 64 - 1);
    if (pf) {
      nk = *(const i32x4*)(ksrc + (size_t)(t + 1) * 64 * NDK);
      nv = *(const i32x4*)(vsrc + (t + 1) * 64);
    }

    // ---- S^T = K * Q^T
    f32x16 st0 = {}, st1 = {};
    __builtin_amdgcn_s_setprio(1);
#pragma unroll
    for (int ks = 0; ks < 4; ks++) {
      int byt = (32 * ks + 16 * hi) ^ swz;
      bf16x8 kf0 = *(const bf16x8*)(Kb + ql * 128 + byt);
      bf16x8 kf1 = *(const bf16x8*)(Kb + (32 + ql) * 128 + byt);
      st0 = __builtin_amdgcn_mfma_f32_32x32x16_bf16(kf0, qf[ks], st0, 0, 0, 0);
      st1 = __builtin_amdgcn_mfma_f32_32x32x16_bf16(kf1, qf[ks], st1, 0, 0, 0);
    }
    __builtin_amdgcn_s_setprio(0);

    // ---- p = exp2(s') directly (scale folded into Q; no max tracking)
#pragma unroll
    for (int r = 0; r < 16; r += 4) {
      float p00 = exp2f(st0[r]),     p01 = exp2f(st0[r + 1]);
      float p02 = exp2f(st0[r + 2]), p03 = exp2f(st0[r + 3]);
      float p10 = exp2f(st1[r]),     p11 = exp2f(st1[r + 1]);
      float p12 = exp2f(st1[r + 2]), p13 = exp2f(st1[r + 3]);
      st0[r] = p00; st0[r + 1] = p01; st0[r + 2] = p02; st0[r + 3] = p03;
      st1[r] = p10; st1[r + 1] = p11; st1[r + 2] = p12; st1[r + 3] = p13;
      ls0 += p00 + p10; ls1 += p01 + p11;
      ls2 += p02 + p12; ls3 += p03 + p13;
    }

    // ---- P -> bf16 B-fragments via permlane32_swap + PV
#pragma unroll
    for (int tt = 0; tt < 2; tt++) {
      f32x16 stv = (tt == 0) ? st0 : st1;
      u32 wv[8];
#pragma unroll
      for (int i = 0; i < 8; i++) wv[i] = pack2(stv[2 * i], stv[2 * i + 1]);
#pragma unroll
      for (int kk = 0; kk < 2; kk++) {
        const int base = 4 * kk;
        i32x2 e0 = pswap(wv[base + 0], wv[base + 2]);
        i32x2 e1 = pswap(wv[base + 1], wv[base + 3]);
        union { u32 u[4]; bf16x8 v; } pf_;
        pf_.u[0] = (u32)e0[0];
        pf_.u[1] = (u32)e1[0];
        pf_.u[2] = (u32)e0[1];
        pf_.u[3] = (u32)e1[1];
        const int ks = 2 * tt + kk;
        int vbyt = (32 * ks + 16 * hi) ^ swz;
        bf16x8 vf0 = *(const bf16x8*)(Vb + ql * 128 + vbyt);
        bf16x8 vf1 = *(const bf16x8*)(Vb + (32 + ql) * 128 + vbyt);
        __builtin_amdgcn_s_setprio(1);
        o0 = __builtin_amdgcn_mfma_f32_32x32x16_bf16(vf0, pf_.v, o0, 0, 0, 0);
        o1 = __builtin_amdgcn_mfma_f32_32x32x16_bf16(vf1, pf_.v, o1, 0, 0, 0);
        __builtin_amdgcn_s_setprio(0);
      }
    }

    // ---- write next tile to the other buffer (vmcnt wait is data-driven)
    if (pf) {
      *(i32x4*)&lK[cur ^ 1][tid * 8] = nk;
      *(i32x4*)&lV[cur ^ 1][tid * 8] = nv;
    }
    asm volatile("s_waitcnt lgkmcnt(0)" ::: "memory");
    __builtin_amdgcn_sched_barrier(0);
    __builtin_amdgcn_s_barrier();
  }

  // ---- epilogue: combine halves of the row-sum once, normalize, store
  float ls = (ls0 + ls1) + (ls2 + ls3);
  float lR;
  {
    i32x2 sr2 = pswap((u32)__float_as_int(ls), (u32)__float_as_int(ls));
    float lsp = __int_as_float(hi ? sr2[0] : sr2[1]);
    float lo_ = hi ? lsp : ls, hi_ = hi ? ls : lsp;
    lR = lo_ + hi_;
  }
  float invl = 1.0f / lR;
  int b_ = bh >> 4, h_ = bh & 15;
  bf16* ob = o + ((size_t)(b_ * NS + qrow) * (NH * NDK)) + h_ * NDK;
#pragma unroll
  for (int rp = 0; rp < 8; rp++) {
    int dv = 8 * (rp >> 1) + 2 * (rp & 1) + 4 * hi;
    *(u32*)&ob[dv]      = pack2(o0[2 * rp] * invl, o0[2 * rp + 1] * invl);
    *(u32*)&ob[dv + 32] = pack2(o1[2 * rp] * invl, o1[2 * rp + 1] * invl);
  }
}

// ---------------------------------------------------------------- LN(residual)
// AF32: residual input dtype (1 = f32, 0 = bf16). WF32: output f32 (else bf16).
template<int AF32, int WF32>
__global__ __launch_bounds__(256)
void ln_res(const void* __restrict__ a_, const bf16* __restrict__ b,
            const float* __restrict__ g, const float* __restrict__ be,
            float* __restrict__ y, bf16* __restrict__ yb) {
  int row = blockIdx.x;
  int tid = threadIdx.x;
  float a0, a1, a2, a3;
  if (AF32) {
    float4 av = ((const float4*)((const float*)a_ + (size_t)row * ND))[tid];
    a0 = av.x; a1 = av.y; a2 = av.z; a3 = av.w;
  } else {
    bf16x4 av = *(const bf16x4*)((const bf16*)a_ + (size_t)row * ND + tid * 4);
    a0 = (float)av[0]; a1 = (float)av[1]; a2 = (float)av[2]; a3 = (float)av[3];
  }
  bf16x4 bv = *(const bf16x4*)(b + (size_t)row * ND + tid * 4);
  float x0 = a0 + (float)bv[0], x1 = a1 + (float)bv[1];
  float x2 = a2 + (float)bv[2], x3 = a3 + (float)bv[3];
  float s = x0 + x1 + x2 + x3;
  float qq_ = x0 * x0 + x1 * x1 + x2 * x2 + x3 * x3;
#pragma unroll
  for (int d = 1; d < 64; d <<= 1) { s += __shfl_xor(s, d); qq_ += __shfl_xor(qq_, d); }
  __shared__ float ss[4], sq[4];
  int w = tid >> 6, lane = tid & 63;
  if (lane == 0) { ss[w] = s; sq[w] = qq_; }
  __syncthreads();
  s = ss[0] + ss[1] + ss[2] + ss[3];
  qq_ = sq[0] + sq[1] + sq[2] + sq[3];
  float mu = s * (1.0f / ND);
  float var = qq_ * (1.0f / ND) - mu * mu;
  float rs = 1.0f / sqrtf(var + 1e-5f);
  const float4* g4 = (const float4*)g;
  const float4* e4 = (const float4*)be;
  float4 gv = g4[tid], ev = e4[tid];
  float o0 = (x0 - mu) * rs * gv.x + ev.x;
  float o1 = (x1 - mu) * rs * gv.y + ev.y;
  float o2 = (x2 - mu) * rs * gv.z + ev.z;
  float o3 = (x3 - mu) * rs * gv.w + ev.w;
  if (WF32) {
    float4 ov = {o0, o1, o2, o3};
    *(float4*)(y + (size_t)row * ND + tid * 4) = ov;
  } else {
    bf16x4 wv;
    wv[0] = (bf16)o0; wv[1] = (bf16)o1; wv[2] = (bf16)o2; wv[3] = (bf16)o3;
    *(bf16x4*)&yb[(size_t)row * ND + tid * 4] = wv;
  }
}

// ---------------------------------------------------------------- launch
extern "C" void kernel_launch(void* const* d_in, const int* in_sizes, int n_in,
                              void* d_out, int out_size, void* d_ws, size_t ws_size,
                              hipStream_t stream) {
  const float* src = (const float*)d_in[0];
  const float* wq  = (const float*)d_in[1];
  const float* bq  = (const float*)d_in[2];
  const float* wk  = (const float*)d_in[3];
  const float* bk  = (const float*)d_in[4];
  const float* wv  = (const float*)d_in[5];
  const float* bv  = (const float*)d_in[6];
  const float* wo  = (const float*)d_in[7];
  const float* bo  = (const float*)d_in[8];
  const float* g1  = (const float*)d_in[9];
  const float* be1 = (const float*)d_in[10];
  const float* w1  = (const float*)d_in[11];
  const float* b1  = (const float*)d_in[12];
  const float* w2  = (const float*)d_in[13];
  const float* b2  = (const float*)d_in[14];
  const float* g2  = (const float*)d_in[15];
  const float* be2 = (const float*)d_in[16];

  char* ws = (char*)d_ws;
  bf16*  srcb  = (bf16*)(ws + 0);            // 16 MiB
  bf16*  wqkvT = (bf16*)(ws + 16777216);     // 6 MiB  [3072][1024]
  bf16*  woT   = (bf16*)(ws + 23068672);     // 2 MiB  [1024][1024]
  bf16*  w1T   = (bf16*)(ws + 25165824);     // 8 MiB  [4096][1024]
  bf16*  w2T   = (bf16*)(ws + 33554432);     // 8 MiB  [1024][4096]
  bf16*  qkv   = (bf16*)(ws + 41943040);     // 48 MiB q|k|(v unused) [BH][S][DK]
  bf16*  vT    = (bf16*)(ws + 92274688);     // 16 MiB [BH][DK][S] (written by EPI0)
  bf16*  attno = (bf16*)(ws + 109051904);    // 16 MiB [B][S][H*DK]
  bf16*  tmpb  = (bf16*)(ws + 125829120);    // 16 MiB attn_out / ff (bf16)
  bf16*  xb    = (bf16*)(ws + 192937984);    // 16 MiB residual x (bf16)
  bf16*  hbuf  = qkv;                         // 64 MiB alias (qkv+vT dead after attn)

  const size_t QKVSZ = (size_t)NB * NH * NS * NDK;

  prep_all<<<20480, 256, 0, stream>>>(src, srcb, wq, wk, wv, wqkvT,
                                      wo, woT, w1, w1T, w2, w2T);

  // QKV projection: BN=128 (grid 768 = 3 full dispatch-waves, tail-free);
  // V written transposed directly to vT by the epilogue.
  gemm8p<128, 0><<<768, 512, 0, stream>>>(srcb, wqkvT, bq, bk, bv, qkv, vT, NM, 3072, 1024);
  flash_attn7<<<512, 512, 0, stream>>>(qkv, qkv + QKVSZ, vT, attno);
  gemm8p<128, 3><<<256, 512, 0, stream>>>(attno, woT, bo, nullptr, nullptr, tmpb, nullptr, NM, 1024, 1024);
  ln_res<1, 0><<<8192, 256, 0, stream>>>(src, tmpb, g1, be1, nullptr, xb);
  gemm8p<256, 1><<<512, 512, 0, stream>>>(xb, w1T, b1, nullptr, nullptr, hbuf, nullptr, NM, 4096, 1024);
  gemm8p<128, 3><<<256, 512, 0, stream>>>(hbuf, w2T, b2, nullptr, nullptr, tmpb, nullptr, NM, 1024, 4096);
  ln_res<0, 1><<<8192, 256, 0, stream>>>(xb, tmpb, g2, be2, (float*)d_out, nullptr);
}

// Round 14
// 426.836 us; speedup vs baseline: 1.0271x; 1.0271x over previous
//
#include <hip/hip_runtime.h>

typedef __bf16 bf16;
typedef __bf16 bf16x8 __attribute__((ext_vector_type(8)));
typedef __bf16 bf16x4 __attribute__((ext_vector_type(4)));
typedef float  f32x4  __attribute__((ext_vector_type(4)));
typedef float  f32x16 __attribute__((ext_vector_type(16)));
typedef unsigned int u32;
typedef int i32x2 __attribute__((ext_vector_type(2)));
typedef int i32x4 __attribute__((ext_vector_type(4)));

#define NB 4
#define NS 2048
#define ND 1024
#define NH 16
#define NDK 64
#define NFF 4096
#define NM (NB*NS)   // 8192 rows

// scale folded into Q projection: (1/sqrt(64)) * log2(e)
#define QSCALE 0.18033688f

__device__ __forceinline__ void load_lds16(const void* g, void* l) {
  __builtin_amdgcn_global_load_lds(
      (const __attribute__((address_space(1))) void*)g,
      (__attribute__((address_space(3))) void*)l, 16, 0, 0);
}

__device__ __forceinline__ u32 pack2(float a, float b) {
  union { bf16 h[2]; u32 u; } z;
  z.h[0] = (bf16)a; z.h[1] = (bf16)b;
  return z.u;
}

__device__ __forceinline__ i32x2 pswap(u32 a, u32 b) {
#if __has_builtin(__builtin_amdgcn_permlane32_swap)
  return __builtin_amdgcn_permlane32_swap((int)a, (int)b, false, false);
#else
  u32 x = a, y = b;
  asm volatile("v_permlane32_swap_b32 %0, %1" : "+v"(x), "+v"(y));
  i32x2 r; r[0] = (int)x; r[1] = (int)y; return r;
#endif
}

// ---------------------------------------------------------------- prep (merged)
__device__ __forceinline__ void tc_body(const float* __restrict__ ip,
                                        bf16* __restrict__ op, int R, int C,
                                        float (*t)[33], int tid) {
  int x = tid & 31, y = tid >> 5;
#pragma unroll
  for (int yy = 0; yy < 32; yy += 8)
    t[y + yy][x] = ip[(size_t)(y + yy) * C + x];
  __syncthreads();
#pragma unroll
  for (int yy = 0; yy < 32; yy += 8)
    op[(size_t)(y + yy) * R + x] = (bf16)t[x][y + yy];
}

__global__ __launch_bounds__(256)
void prep_all(const float* __restrict__ src, bf16* __restrict__ srcb,
              const float* __restrict__ wq, const float* __restrict__ wk,
              const float* __restrict__ wv, bf16* __restrict__ wqkvT,
              const float* __restrict__ wo, bf16* __restrict__ woT,
              const float* __restrict__ w1, bf16* __restrict__ w1T,
              const float* __restrict__ w2, bf16* __restrict__ w2T) {
  __shared__ float t[32][33];
  const int id = blockIdx.x, tid = threadIdx.x;
  if (id < 8192) {
    int i = (id * 256 + tid) * 4;
    float4 v = *(const float4*)&src[i];
    bf16x4 o;
    o[0] = (bf16)v.x; o[1] = (bf16)v.y; o[2] = (bf16)v.z; o[3] = (bf16)v.w;
    *(bf16x4*)&srcb[i] = o;
    return;
  }
  int id2 = id - 8192;
  if (id2 < 3072) {
    int wsel = id2 >> 10, r = id2 & 1023;
    int bz = r >> 6, by = (r >> 5) & 1, bx = r & 31;
    const float* w = (wsel == 0) ? wq : (wsel == 1) ? wk : wv;
    const float* ip = w + (size_t)bz * 65536 + (size_t)(bx * 32) * 64 + by * 32;
    bf16* op = wqkvT + (size_t)wsel * 1048576 + (size_t)bz * 65536 +
               (size_t)(by * 32) * 1024 + bx * 32;
    tc_body(ip, op, 1024, 64, t, tid);
    return;
  }
  id2 -= 3072;
  if (id2 < 1024) {
    int bx = id2 & 31, by = id2 >> 5;
    const float* ip = wo + (size_t)(bx * 32) * 1024 + by * 32;
    bf16* op = woT + (size_t)(by * 32) * 1024 + bx * 32;
    tc_body(ip, op, 1024, 1024, t, tid);
    return;
  }
  id2 -= 1024;
  if (id2 < 4096) {
    int bx = id2 & 31, by = id2 >> 5;
    const float* ip = w1 + (size_t)(bx * 32) * 4096 + by * 32;
    bf16* op = w1T + (size_t)(by * 32) * 1024 + bx * 32;
    tc_body(ip, op, 1024, 4096, t, tid);
    return;
  }
  id2 -= 4096;
  {
    int bx = id2 & 127, by = id2 >> 7;
    const float* ip = w2 + (size_t)(bx * 32) * 1024 + by * 32;
    bf16* op = w2T + (size_t)(by * 32) * 4096 + bx * 32;
    tc_body(ip, op, 4096, 1024, t, tid);
  }
}

// ---------------------------------------------------------------- GEMM 8-phase
#define BAR()  __builtin_amdgcn_s_barrier()
#define LGKM0() do { asm volatile("s_waitcnt lgkmcnt(0)" ::: "memory"); \
                     __builtin_amdgcn_sched_barrier(0); } while (0)

// EPI 0: QKV scatter (q/k rows bf16 + QSCALE on q; V written TRANSPOSED to out1)
// EPI 1: bf16+relu; EPI 2: f32+bias; EPI 3: bf16+bias
template<int BN, int EPI>
__global__ __launch_bounds__(512, 2)
void gemm8p(const bf16* __restrict__ A, const bf16* __restrict__ Bt,
            const float* __restrict__ bias0, const float* __restrict__ bias1,
            const float* __restrict__ bias2, void* __restrict__ out0,
            void* __restrict__ out1, int M, int N, int K) {
  constexpr int NFR = BN / 64;          // n-frags per wave (4 or 2)
  __shared__ __align__(16) bf16 lA[2][256 * 64];
  __shared__ __align__(16) bf16 lB[2][BN * 64];

  const int tid = threadIdx.x, lane = tid & 63, w = tid >> 6;
  const int wr = w >> 2, wn = w & 3;
  const int blane = lane & 15, glane = lane >> 4;

  const int nwg = gridDim.x;
  const int cpx = nwg >> 3;
  const int bid = blockIdx.x;
  const int swzb = (bid & 7) * cpx + (bid >> 3);
  const int gridM = M >> 8;
  const int bm = (swzb % gridM) * 256;
  const int bn = (swzb / gridM) * BN;

  f32x4 acc[8][NFR] = {};
  bf16x8 aF[8], bF[2 * NFR];

  auto stageA = [&](int kt, int h, int b) {
#pragma unroll
    for (int j = 0; j < 2; j++) {
      int ch = w * 128 + j * 64 + lane;
      int r = h * 128 + (ch >> 3), s = ch & 7;
      load_lds16(A + (size_t)(bm + r) * K + kt * 64 + ((s ^ (r & 7)) * 8),
                 &lA[b][(h * 1024 + ch) * 8]);
    }
  };
  auto stageB = [&](int kt, int h, int b) {
    if constexpr (BN == 256) {
#pragma unroll
      for (int j = 0; j < 2; j++) {
        int ch = w * 128 + j * 64 + lane;
        int r = h * 128 + (ch >> 3), s = ch & 7;
        load_lds16(Bt + (size_t)(bn + r) * K + kt * 64 + ((s ^ (r & 7)) * 8),
                   &lB[b][(h * 1024 + ch) * 8]);
      }
    } else {
      int ch = w * 64 + lane;
      int r = h * 64 + (ch >> 3), s = ch & 7;
      load_lds16(Bt + (size_t)(bn + r) * K + kt * 64 + ((s ^ (r & 7)) * 8),
                 &lB[b][(h * 512 + ch) * 8]);
    }
  };
  auto vmwait = [&]() {
    if constexpr (BN == 256) asm volatile("s_waitcnt vmcnt(6)" ::: "memory");
    else                     asm volatile("s_waitcnt vmcnt(4)" ::: "memory");
  };
  auto ldA = [&](int mh, int b) {
#pragma unroll
    for (int mf = 0; mf < 4; mf++)
#pragma unroll
      for (int ks = 0; ks < 2; ks++) {
        int r = wr * 128 + mh * 64 + mf * 16 + blane;
        int s = (ks * 4 + glane) ^ (r & 7);
        aF[mf * 2 + ks] = *(const bf16x8*)&lA[b][r * 64 + s * 8];
      }
  };
  auto ldBh = [&](int nh, int b) {
#pragma unroll
    for (int nq = 0; nq < NFR / 2; nq++)
#pragma unroll
      for (int ks = 0; ks < 2; ks++) {
        int nf = nh * (NFR / 2) + nq;
        int r = wn * (NFR * 16) + nf * 16 + blane;
        int s = (ks * 4 + glane) ^ (r & 7);
        bF[nf * 2 + ks] = *(const bf16x8*)&lB[b][r * 64 + s * 8];
      }
  };

#define MMAQ(mh, nh)  do {                                                  \
    __builtin_amdgcn_s_setprio(1);                                          \
    _Pragma("unroll")                                                       \
    for (int mf = 0; mf < 4; mf++)                                          \
      _Pragma("unroll")                                                     \
      for (int nq = 0; nq < NFR / 2; nq++)                                  \
        _Pragma("unroll")                                                   \
        for (int ks = 0; ks < 2; ks++)                                      \
          acc[(mh) * 4 + mf][(nh) * (NFR / 2) + nq] =                       \
            __builtin_amdgcn_mfma_f32_16x16x32_bf16(                        \
              aF[mf * 2 + ks], bF[((nh) * (NFR / 2) + nq) * 2 + ks],        \
              acc[(mh) * 4 + mf][(nh) * (NFR / 2) + nq], 0, 0, 0);          \
    __builtin_amdgcn_s_setprio(0);                                          \
  } while (0)

  // ---- prologue: tile0 full + tile1 {B0,B1,A0}
  stageB(0, 0, 0); stageB(0, 1, 0); stageA(0, 0, 0); stageA(0, 1, 0);
  stageB(1, 0, 1); stageB(1, 1, 1); stageA(1, 0, 1);
  vmwait();
  BAR();

  const int NT = K >> 6;
  for (int u = 0; u < NT; u += 2) {
    const int t2 = (u + 2 < NT) ? u + 2 : u;
    const int t3 = (u + 3 < NT) ? u + 3 : u + 1;
    // P1
    ldA(0, 0); ldBh(0, 0);
    stageA(u + 1, 1, 1);
    BAR(); LGKM0(); MMAQ(0, 0); BAR();
    // P2
    ldBh(1, 0);
    stageB(t2, 0, 0);
    BAR(); LGKM0(); MMAQ(0, 1); BAR();
    // P3
    ldA(1, 0);
    stageB(t2, 1, 0);
    BAR(); LGKM0(); MMAQ(1, 1); BAR();
    // P4
    stageA(t2, 0, 0);
    BAR(); MMAQ(1, 0); vmwait(); BAR();
    // P5
    ldA(0, 1); ldBh(0, 1);
    stageA(t2, 1, 0);
    BAR(); LGKM0(); MMAQ(0, 0); BAR();
    // P6
    ldBh(1, 1);
    stageB(t3, 0, 1);
    BAR(); LGKM0(); MMAQ(0, 1); BAR();
    // P7
    ldA(1, 1);
    stageB(t3, 1, 1);
    BAR(); LGKM0(); MMAQ(1, 1); BAR();
    // P8
    stageA(t3, 0, 1);
    BAR(); MMAQ(1, 0); vmwait(); BAR();
  }

  // ---- epilogue
#pragma unroll
  for (int am = 0; am < 8; am++) {
#pragma unroll
    for (int nf = 0; nf < NFR; nf++) {
      int col = bn + wn * (NFR * 16) + nf * 16 + blane;
      int rowb = bm + wr * 128 + (am >> 2) * 64 + (am & 3) * 16 + glane * 4;
      if (EPI == 0) {
        int sel = col >> 10;
        int hh = (col & 1023) >> 6;
        int dv = col & 63;
        int b_ = rowb >> 11, s_ = rowb & 2047;
        if (sel == 2) {
          // V: write transposed directly (vT[bh][dv][s]); s contiguous -> packed
          float bias = bias2[col & 1023];
          bf16* vt = (bf16*)out1;
          bf16* p = vt + (((size_t)(b_ * NH + hh) * NDK + dv) * NS) + s_;
          *(u32*)p       = pack2(acc[am][nf][0] + bias, acc[am][nf][1] + bias);
          *(u32*)(p + 2) = pack2(acc[am][nf][2] + bias, acc[am][nf][3] + bias);
        } else {
          const float* bp = (sel == 0) ? bias0 : bias1;
          float bias = bp[col & 1023];
          float sc = (sel == 0) ? QSCALE : 1.0f;   // fold softmax scale into Q
          bf16* outb = (bf16*)out0 + (size_t)sel * NB * NH * NS * NDK;
#pragma unroll
          for (int i = 0; i < 4; i++) {
            outb[(((size_t)(b_ * NH + hh) * NS + (s_ + i)) * NDK) + dv] =
                (bf16)((acc[am][nf][i] + bias) * sc);
          }
        }
      } else if (EPI == 1) {
        float bias = bias0[col];
#pragma unroll
        for (int i = 0; i < 4; i++) {
          float v = acc[am][nf][i] + bias;
          v = v > 0.f ? v : 0.f;
          ((bf16*)out0)[(size_t)(rowb + i) * N + col] = (bf16)v;
        }
      } else if (EPI == 2) {
        float bias = bias0[col];
#pragma unroll
        for (int i = 0; i < 4; i++)
          ((float*)out0)[(size_t)(rowb + i) * N + col] = acc[am][nf][i] + bias;
      } else {
        float bias = bias0[col];
#pragma unroll
        for (int i = 0; i < 4; i++)
          ((bf16*)out0)[(size_t)(rowb + i) * N + col] = (bf16)(acc[am][nf][i] + bias);
      }
    }
  }
#undef MMAQ
}

// ---------------------------------------------------------------- flash attn v7
// T14 async-STAGE split (global->reg->LDS), raw barriers (no vmcnt drain),
// 8 waves x 32 q-rows (QBLK=256), bh-clustered XCD decode, static-max softmax.
__global__ __launch_bounds__(512)
void flash_attn7(const bf16* __restrict__ q, const bf16* __restrict__ k,
                 const bf16* __restrict__ vT, bf16* __restrict__ o) {
  __shared__ __align__(16) bf16 lK[2][64 * 64];
  __shared__ __align__(16) bf16 lV[2][64 * 64];
  const int tid = threadIdx.x, lane = tid & 63, w = tid >> 6;
  const int ql = lane & 31, hi = lane >> 5;

  // XCD-clustered decode: each XCD owns 8 heads; 8 qt-blocks per head.
  const int id = blockIdx.x;
  const int xcd = id & 7, sseq = id >> 3;      // sseq 0..63
  const int bh = xcd * 8 + (sseq >> 3);
  const int qt = sseq & 7;

  const size_t hb = (size_t)bh * NS * NDK;
  const int qrow = qt * 256 + w * 32 + ql;

  // Q fragments: B-operand, col=q (lane-local), k = d = 16*ks + 8*hi + j
  bf16x8 qf[4];
#pragma unroll
  for (int ks = 0; ks < 4; ks++)
    qf[ks] = *(const bf16x8*)&q[hb + (size_t)qrow * NDK + ks * 16 + hi * 8];

  // reg-staging source (pre-swizzled 16B chunk within 128B row)
  const int sr = tid >> 3, sc = ((tid & 7) ^ (sr & 7)) * 8;
  const bf16* ksrc = k  + hb + (size_t)sr * NDK + sc;
  const bf16* vsrc = vT + hb + (size_t)sr * NS  + sc;

  f32x16 o0 = {}, o1 = {};
  float ls0 = 0.f, ls1 = 0.f, ls2 = 0.f, ls3 = 0.f;
  const int swz = (ql & 7) << 4;

  // ---- prologue: stage tile 0 via regs
  {
    i32x4 rk = *(const i32x4*)ksrc;
    i32x4 rv = *(const i32x4*)vsrc;
    *(i32x4*)&lK[0][tid * 8] = rk;
    *(i32x4*)&lV[0][tid * 8] = rv;
  }
  asm volatile("s_waitcnt lgkmcnt(0)" ::: "memory");
  __builtin_amdgcn_sched_barrier(0);
  __builtin_amdgcn_s_barrier();

  const char* lKc = (const char*)&lK[0][0];
  const char* lVc = (const char*)&lV[0][0];

  for (int t = 0; t < NS / 64; t++) {
    const int cur = t & 1;
    const char* Kb = lKc + cur * 8192;
    const char* Vb = lVc + cur * 8192;

    // ---- issue next-tile loads early (latency hides under softmax+PV)
    i32x4 nk, nv;
    const bool pf = (t < NS / 64 - 1);
    if (pf) {
      nk = *(const i32x4*)(ksrc + (size_t)(t + 1) * 64 * NDK);
      nv = *(const i32x4*)(vsrc + (t + 1) * 64);
    }

    // ---- S^T = K * Q^T
    f32x16 st0 = {}, st1 = {};
    __builtin_amdgcn_s_setprio(1);
#pragma unroll
    for (int ks = 0; ks < 4; ks++) {
      int byt = (32 * ks + 16 * hi) ^ swz;
      bf16x8 kf0 = *(const bf16x8*)(Kb + ql * 128 + byt);
      bf16x8 kf1 = *(const bf16x8*)(Kb + (32 + ql) * 128 + byt);
      st0 = __builtin_amdgcn_mfma_f32_32x32x16_bf16(kf0, qf[ks], st0, 0, 0, 0);
      st1 = __builtin_amdgcn_mfma_f32_32x32x16_bf16(kf1, qf[ks], st1, 0, 0, 0);
    }
    __builtin_amdgcn_s_setprio(0);

    // ---- p = exp2(s') directly (scale folded into Q; no max tracking)
#pragma unroll
    for (int r = 0; r < 16; r += 4) {
      float p00 = exp2f(st0[r]),     p01 = exp2f(st0[r + 1]);
      float p02 = exp2f(st0[r + 2]), p03 = exp2f(st0[r + 3]);
      float p10 = exp2f(st1[r]),     p11 = exp2f(st1[r + 1]);
      float p12 = exp2f(st1[r + 2]), p13 = exp2f(st1[r + 3]);
      st0[r] = p00; st0[r + 1] = p01; st0[r + 2] = p02; st0[r + 3] = p03;
      st1[r] = p10; st1[r + 1] = p11; st1[r + 2] = p12; st1[r + 3] = p13;
      ls0 += p00 + p10; ls1 += p01 + p11;
      ls2 += p02 + p12; ls3 += p03 + p13;
    }

    // ---- P -> bf16 B-fragments via permlane32_swap + PV
#pragma unroll
    for (int tt = 0; tt < 2; tt++) {
      f32x16 stv = (tt == 0) ? st0 : st1;
      u32 wv[8];
#pragma unroll
      for (int i = 0; i < 8; i++) wv[i] = pack2(stv[2 * i], stv[2 * i + 1]);
#pragma unroll
      for (int kk = 0; kk < 2; kk++) {
        const int base = 4 * kk;
        i32x2 e0 = pswap(wv[base + 0], wv[base + 2]);
        i32x2 e1 = pswap(wv[base + 1], wv[base + 3]);
        union { u32 u[4]; bf16x8 v; } pf_;
        pf_.u[0] = (u32)e0[0];
        pf_.u[1] = (u32)e1[0];
        pf_.u[2] = (u32)e0[1];
        pf_.u[3] = (u32)e1[1];
        const int ks = 2 * tt + kk;
        int vbyt = (32 * ks + 16 * hi) ^ swz;
        bf16x8 vf0 = *(const bf16x8*)(Vb + ql * 128 + vbyt);
        bf16x8 vf1 = *(const bf16x8*)(Vb + (32 + ql) * 128 + vbyt);
        __builtin_amdgcn_s_setprio(1);
        o0 = __builtin_amdgcn_mfma_f32_32x32x16_bf16(vf0, pf_.v, o0, 0, 0, 0);
        o1 = __builtin_amdgcn_mfma_f32_32x32x16_bf16(vf1, pf_.v, o1, 0, 0, 0);
        __builtin_amdgcn_s_setprio(0);
      }
    }

    // ---- write next tile to the other buffer (vmcnt wait is data-driven)
    if (pf) {
      *(i32x4*)&lK[cur ^ 1][tid * 8] = nk;
      *(i32x4*)&lV[cur ^ 1][tid * 8] = nv;
    }
    asm volatile("s_waitcnt lgkmcnt(0)" ::: "memory");
    __builtin_amdgcn_sched_barrier(0);
    __builtin_amdgcn_s_barrier();
  }

  // ---- epilogue: combine halves of the row-sum once, normalize, store
  float ls = (ls0 + ls1) + (ls2 + ls3);
  float lR;
  {
    i32x2 sr2 = pswap((u32)__float_as_int(ls), (u32)__float_as_int(ls));
    float lsp = __int_as_float(hi ? sr2[0] : sr2[1]);
    float lo_ = hi ? lsp : ls, hi_ = hi ? ls : lsp;
    lR = lo_ + hi_;
  }
  float invl = 1.0f / lR;
  int b_ = bh >> 4, h_ = bh & 15;
  bf16* ob = o + ((size_t)(b_ * NS + qrow) * (NH * NDK)) + h_ * NDK;
#pragma unroll
  for (int rp = 0; rp < 8; rp++) {
    int dv = 8 * (rp >> 1) + 2 * (rp & 1) + 4 * hi;
    *(u32*)&ob[dv]      = pack2(o0[2 * rp] * invl, o0[2 * rp + 1] * invl);
    *(u32*)&ob[dv + 32] = pack2(o1[2 * rp] * invl, o1[2 * rp + 1] * invl);
  }
}

// ---------------------------------------------------------------- LN(residual)
// AF32: residual input dtype (1 = f32, 0 = bf16). WF32: output f32 (else bf16).
template<int AF32, int WF32>
__global__ __launch_bounds__(256)
void ln_res(const void* __restrict__ a_, const bf16* __restrict__ b,
            const float* __restrict__ g, const float* __restrict__ be,
            float* __restrict__ y, bf16* __restrict__ yb) {
  int row = blockIdx.x;
  int tid = threadIdx.x;
  float a0, a1, a2, a3;
  if (AF32) {
    float4 av = ((const float4*)((const float*)a_ + (size_t)row * ND))[tid];
    a0 = av.x; a1 = av.y; a2 = av.z; a3 = av.w;
  } else {
    bf16x4 av = *(const bf16x4*)((const bf16*)a_ + (size_t)row * ND + tid * 4);
    a0 = (float)av[0]; a1 = (float)av[1]; a2 = (float)av[2]; a3 = (float)av[3];
  }
  bf16x4 bv = *(const bf16x4*)(b + (size_t)row * ND + tid * 4);
  float x0 = a0 + (float)bv[0], x1 = a1 + (float)bv[1];
  float x2 = a2 + (float)bv[2], x3 = a3 + (float)bv[3];
  float s = x0 + x1 + x2 + x3;
  float qq_ = x0 * x0 + x1 * x1 + x2 * x2 + x3 * x3;
#pragma unroll
  for (int d = 1; d < 64; d <<= 1) { s += __shfl_xor(s, d); qq_ += __shfl_xor(qq_, d); }
  __shared__ float ss[4], sq[4];
  int w = tid >> 6, lane = tid & 63;
  if (lane == 0) { ss[w] = s; sq[w] = qq_; }
  __syncthreads();
  s = ss[0] + ss[1] + ss[2] + ss[3];
  qq_ = sq[0] + sq[1] + sq[2] + sq[3];
  float mu = s * (1.0f / ND);
  float var = qq_ * (1.0f / ND) - mu * mu;
  float rs = 1.0f / sqrtf(var + 1e-5f);
  const float4* g4 = (const float4*)g;
  const float4* e4 = (const float4*)be;
  float4 gv = g4[tid], ev = e4[tid];
  float o0 = (x0 - mu) * rs * gv.x + ev.x;
  float o1 = (x1 - mu) * rs * gv.y + ev.y;
  float o2 = (x2 - mu) * rs * gv.z + ev.z;
  float o3 = (x3 - mu) * rs * gv.w + ev.w;
  if (WF32) {
    float4 ov = {o0, o1, o2, o3};
    *(float4*)(y + (size_t)row * ND + tid * 4) = ov;
  } else {
    bf16x4 wv;
    wv[0] = (bf16)o0; wv[1] = (bf16)o1; wv[2] = (bf16)o2; wv[3] = (bf16)o3;
    *(bf16x4*)&yb[(size_t)row * ND + tid * 4] = wv;
  }
}

// ---------------------------------------------------------------- launch
extern "C" void kernel_launch(void* const* d_in, const int* in_sizes, int n_in,
                              void* d_out, int out_size, void* d_ws, size_t ws_size,
                              hipStream_t stream) {
  const float* src = (const float*)d_in[0];
  const float* wq  = (const float*)d_in[1];
  const float* bq  = (const float*)d_in[2];
  const float* wk  = (const float*)d_in[3];
  const float* bk  = (const float*)d_in[4];
  const float* wv  = (const float*)d_in[5];
  const float* bv  = (const float*)d_in[6];
  const float* wo  = (const float*)d_in[7];
  const float* bo  = (const float*)d_in[8];
  const float* g1  = (const float*)d_in[9];
  const float* be1 = (const float*)d_in[10];
  const float* w1  = (const float*)d_in[11];
  const float* b1  = (const float*)d_in[12];
  const float* w2  = (const float*)d_in[13];
  const float* b2  = (const float*)d_in[14];
  const float* g2  = (const float*)d_in[15];
  const float* be2 = (const float*)d_in[16];

  char* ws = (char*)d_ws;
  bf16*  srcb  = (bf16*)(ws + 0);            // 16 MiB
  bf16*  wqkvT = (bf16*)(ws + 16777216);     // 6 MiB  [3072][1024]
  bf16*  woT   = (bf16*)(ws + 23068672);     // 2 MiB  [1024][1024]
  bf16*  w1T   = (bf16*)(ws + 25165824);     // 8 MiB  [4096][1024]
  bf16*  w2T   = (bf16*)(ws + 33554432);     // 8 MiB  [1024][4096]
  bf16*  qkv   = (bf16*)(ws + 41943040);     // 48 MiB q|k|(v unused) [BH][S][DK]
  bf16*  vT    = (bf16*)(ws + 92274688);     // 16 MiB [BH][DK][S] (written by EPI0)
  bf16*  attno = (bf16*)(ws + 109051904);    // 16 MiB [B][S][H*DK]
  bf16*  tmpb  = (bf16*)(ws + 125829120);    // 16 MiB attn_out / ff (bf16)
  bf16*  xb    = (bf16*)(ws + 192937984);    // 16 MiB residual x (bf16)
  bf16*  hbuf  = qkv;                         // 64 MiB alias (qkv+vT dead after attn)

  const size_t QKVSZ = (size_t)NB * NH * NS * NDK;

  prep_all<<<20480, 256, 0, stream>>>(src, srcb, wq, wk, wv, wqkvT,
                                      wo, woT, w1, w1T, w2, w2T);

  // QKV projection: BN=256 (grid 384); V written transposed directly by EPI0.
  gemm8p<256, 0><<<384, 512, 0, stream>>>(srcb, wqkvT, bq, bk, bv, qkv, vT, NM, 3072, 1024);
  flash_attn7<<<512, 512, 0, stream>>>(qkv, qkv + QKVSZ, vT, attno);
  gemm8p<128, 3><<<256, 512, 0, stream>>>(attno, woT, bo, nullptr, nullptr, tmpb, nullptr, NM, 1024, 1024);
  ln_res<1, 0><<<8192, 256, 0, stream>>>(src, tmpb, g1, be1, nullptr, xb);
  gemm8p<256, 1><<<512, 512, 0, stream>>>(xb, w1T, b1, nullptr, nullptr, hbuf, nullptr, NM, 4096, 1024);
  gemm8p<128, 3><<<256, 512, 0, stream>>>(hbuf, w2T, b2, nullptr, nullptr, tmpb, nullptr, NM, 1024, 4096);
  ln_res<0, 1><<<8192, 256, 0, stream>>>(xb, tmpb, g2, be2, (float*)d_out, nullptr);
}